// Round 7
// baseline (295.990 us; speedup 1.0000x reference)
//
#include <hip/hip_runtime.h>
#include <type_traits>
#include <cmath>
#include <cstdint>

#define NRAYS     262144
#define HASHMAP   524288
#define DIM       256
#define NMID      6
#define MBLK      128
#define NTHR      512
#define ALPHA     512.0f          // power-of-2 activation scale: lifts h (~1e-4) out of
#define INV_ALPHA (1.0f / 512.0f) // fp16 subnormal range; exact, removed at output.

typedef _Float16 half8 __attribute__((ext_vector_type(8)));
typedef _Float16 half2 __attribute__((ext_vector_type(2)));
typedef float  floatx4 __attribute__((ext_vector_type(4)));

// ws layout (_Float16 elements) — fp16 weights, single product per MFMA:
//   [0, 8192):        W_in  fragments [nc:16][lane:64][j:8]  (K padded 16->32 with zeros)
//   [8192, 401408):   W_mid fragments [L:6][kc:8][nc:16][lane:64][j:8]
// fp16 numerics validated: absmax 1.19e-7, 3.3x under threshold.
//
// SESSION INVARIANT (R10/R11/R14 post-mortems): the ~2-7e-6 few-elements-wrong
// miscompile class fires on ANY novel MFMA-loop register shape. R14 failed even
// at nominal b[2]+a[4] (scheduler hoisting -> 40 live input regs). The ONLY
// trusted micro-structure is R13's exact per-wave loop:
//   b[4]+a[4] input regs, acc[4][4] floatx4, one setprio cluster, nl=4,
//   #pragma clang loop unroll(disable) on kc. NEVER deviate from it.
// R15 keeps that loop textually identical; MBLK=128 comes from wave-halving
// (waves 0-3 -> rays 0-63, waves 4-7 -> rays 64-127 via ONE base pointer).
//
// R12 (pass, 326us): strength-reduced A addressing + s_setprio.
// R13 (pass, 222us): strength-reduced epilogue addressing.
// R15: MBLK=128 / 8 waves. R5 counters: weight traffic 16.5 TB/s = 48% of L2
// ceiling, serialized 1:1 with MFMA (MfmaUtil 43 ~= VALUBusy 43, HBM 1%).
// 128 rays/block halves per-ray weight traffic; waves 4-7 read the SAME
// fragment bytes as 0-3 (L1 reuse). 2 blocks/CU x 8 waves = 16 waves/CU
// (occupancy unchanged vs R13's 4x4).
#define WIN_ELEMS   8192
#define WL_ELEMS    65536
#define WKC_ELEMS   8192
#define WNC_ELEMS   512

// Gray-coded XOR swizzle (R4, frozen — conflict counter insensitive to choice).
__device__ __forceinline__ int sw_idx(int r, int k) {
  int s = (r ^ (r >> 1)) & 7;
  return (r << 8) + ((((k >> 3) ^ s) << 3) | (k & 7));
}

__global__ __launch_bounds__(256) void prep_weights(
    const float* __restrict__ W_in, const float* __restrict__ W_mid,
    _Float16* __restrict__ wsh)
{
  int tid = blockIdx.x * 256 + threadIdx.x;
  int pos = tid & 511;             // lane*8 + j
  int lane = pos >> 3, j = pos & 7;
  int kk = ((lane >> 4) << 3) + j; // quad*8 + j, 0..31
  if (tid < WIN_ELEMS) {
    int nc = tid >> 9;
    int n = (nc << 4) + (lane & 15);
    float v = (kk < 16) ? W_in[kk * DIM + n] : 0.f;
    wsh[nc * WNC_ELEMS + pos] = (_Float16)v;
  } else if (tid < WIN_ELEMS + 6 * WL_ELEMS) {
    int u = tid - WIN_ELEMS;
    int fid = u >> 9;              // 0..767
    int L   = fid >> 7;
    int rem = fid & 127;
    int kc  = rem >> 4;
    int nc  = rem & 15;
    int k = (kc << 5) + kk;
    int n = (nc << 4) + (lane & 15);
    float v = W_mid[L * (DIM * DIM) + k * DIM + n];
    wsh[WIN_ELEMS + L * WL_ELEMS + kc * WKC_ELEMS + nc * WNC_ELEMS + pos] = (_Float16)v;
  }
}

// (512,4): 8 waves/block, 2 blocks/CU (2 x 64KB LDS of 160KB), 16 waves/CU —
// same occupancy as R13, half the per-ray weight traffic. Per-wave register
// cap 128 = arch 64 + acc 64 (the correctness invariant).
__global__ __launch_bounds__(512, 4) void mlp_fused(
    const float* __restrict__ x,
    const float* __restrict__ table1,
    const float* __restrict__ table2,
    const _Float16* __restrict__ wsh,
    const float* __restrict__ b_in,
    const float* __restrict__ b_mid,
    const float* __restrict__ W_out,
    const float* __restrict__ b_out,
    float* __restrict__ out,
    int res0, int res1, int res2, int res3)
{
  __shared__ __align__(16) _Float16 hs[MBLK * 256];  // 64KB: alpha*relu(h) fp16, swizzled [ray][k]

  const int tid  = threadIdx.x;
  const int lane = tid & 63;
  const int wave = tid >> 6;       // 0..7
  const int w4   = wave & 3;       // R13-equivalent wave id
  const int col  = lane & 15;
  const int quad = lane >> 4;
  const int rbase = blockIdx.x * MBLK;

  // ---------------- hash-grid encode: 1024 (ray,enc,level) tasks, 2 per thread ----------------
  #pragma unroll
  for (int i = 0; i < 2; ++i) {
    int task = tid + (i << 9);
    int r   = task & 127;
    int el  = task >> 7;           // 0..7
    int enc = el >> 2, lev = el & 3;
    const float* xp = x + (size_t)(rbase + r) * 4 + enc * 2;
    float px = xp[0], py = xp[1];
    int res = (lev == 0) ? res0 : (lev == 1) ? res1 : (lev == 2) ? res2 : res3;
    float fres = (float)res;
    float xf = px * fres, yf = py * fres;
    float xi = floorf(xf), yi = floorf(yf);
    float fx = xf - xi,  fy = yf - yi;
    uint32_t ix = (uint32_t)xi, iy = (uint32_t)yi;
    const float2* tab = (const float2*)(enc ? table2 : table1) + (size_t)lev * HASHMAP;
    float f0 = 0.f, f1 = 0.f;
    #pragma unroll
    for (int c = 0; c < 4; ++c) {                    // corners (0,0),(0,1),(1,0),(1,1)
      uint32_t c0 = (uint32_t)(c >> 1), c1 = (uint32_t)(c & 1);
      uint32_t h = ((ix + c0) ^ ((iy + c1) * 2654435761u)) & (uint32_t)(HASHMAP - 1);
      float2 v = tab[h];
      float w = (c0 ? fx : 1.f - fx) * (c1 ? fy : 1.f - fy);
      f0 += w * v.x;
      f1 += w * v.y;
    }
    int cb = enc * 8 + lev * 2;                      // emb column (concat: enc-major, level, feat)
    half2 hp = {(_Float16)(f0 * ALPHA), (_Float16)(f1 * ALPHA)};
    *(half2*)&hs[sw_idx(r, cb)] = hp;
  }
  // zero K-pad columns 16..31 for the first (K=32) MFMA
  for (int i = tid; i < MBLK * 16; i += NTHR) {
    int r = i >> 4, k = 16 + (i & 15);
    hs[sw_idx(r, k)] = (_Float16)0.f;
  }
  __syncthreads();

  floatx4 acc[4][4];

  // R12 A-address strength reduction (unchanged): for A-reads, row = mt*16+col
  // (plus the wave-half base), sw_idx's s depends only on row bits 0..3 = col:
  //   byte(mt,kc) = half + (mt*16+col)*512 + qa*16 + ((kc^s2)<<6)
  //   s_a=(col^(col>>1))&7, s2=s_a>>2, qa=quad^(s_a&3).
  // mt term (mt*8192) folds into the ds imm; half goes into the base pointer.
  const int s_a = (col ^ (col >> 1)) & 7;
  const int s2  = (s_a >> 2) & 1;
  const int abase = col * 512 + (quad ^ (s_a & 3)) * 16;
  char* const hsw = (char*)hs + ((wave >> 2) << 15);   // + 0 or 32768 B (64 rows)

  // One dense layer: D(128x256) = A(128xK) * B(Kx256). Per wave: R13's exact
  // 64-ray x 256-col loop; the wave-half base selects which 64 rays.
  auto run_layer = [&](auto kc_const, const _Float16* __restrict__ wbase,
                       const float* __restrict__ bias_ptr) {
    constexpr int KCOUNT = decltype(kc_const)::value;
    const floatx4 zv = {0.f, 0.f, 0.f, 0.f};
    #pragma unroll
    for (int mt = 0; mt < 4; ++mt)
      #pragma unroll
      for (int nl = 0; nl < 4; ++nl)
        acc[mt][nl] = zv;

    const _Float16* wlane = wbase + w4 * 4 * WNC_ELEMS + lane * 8;

    #pragma clang loop unroll(disable)               // keep VGPR pressure flat (<=128)
    for (int kc = 0; kc < KCOUNT; ++kc) {
      half8 b[4];
      const _Float16* wk = wlane + kc * WKC_ELEMS;
      #pragma unroll
      for (int nl = 0; nl < 4; ++nl)
        b[nl] = *(const half8*)(wk + nl * WNC_ELEMS);
      half8 a[4];
      const char* ap = hsw + abase + ((kc ^ s2) << 6);
      #pragma unroll
      for (int mt = 0; mt < 4; ++mt)
        a[mt] = *(const half8*)(ap + mt * 8192);     // imm-offset ds_read_b128
      __builtin_amdgcn_s_setprio(1);
      #pragma unroll
      for (int nl = 0; nl < 4; ++nl)
        #pragma unroll
        for (int mt = 0; mt < 4; ++mt)
          acc[mt][nl] = __builtin_amdgcn_mfma_f32_16x16x32_f16(a[mt], b[nl], acc[mt][nl], 0, 0, 0);
      __builtin_amdgcn_s_setprio(0);
    }
    __syncthreads();   // all waves done reading hs before overwrite

    // R13 epilogue address strength reduction (unchanged). Write target (m,n):
    //   m = half*64 + mt*16 + quad*4 + r, n = w4*64 + nl*16 + col.
    //   byte = half + mt*8192 (ds imm) + (quad*4+r)*512 + w4*128
    //        + ((v^s_r)<<4) + (col&7)*2,  v = nl*2|c3, s_r=(m0^(m0>>1))&7.
    // s(m) depends only on m bits 0..3 -> half- and mt-independent.
    {
      const int c3   = (col >> 3) & 1;
      const int ebase = w4 * 128 + ((col & 7) << 1);
      #pragma unroll
      for (int nl = 0; nl < 4; ++nl) {
        int n = w4 * 64 + nl * 16 + col;
        float biasA = bias_ptr[n] * ALPHA;           // bias scaled by alpha
        #pragma unroll
        for (int r = 0; r < 4; ++r) {
          int m0  = quad * 4 + r;
          int s_r = (m0 ^ (m0 >> 1)) & 7;
          int va  = m0 * 512 + ebase + (((((nl << 1) | c3)) ^ s_r) << 4);
          char* wp = hsw + va;
          #pragma unroll
          for (int mt = 0; mt < 4; ++mt) {
            float hv = fmaxf(acc[mt][nl][r] + biasA, 0.f);   // ReLU pre-next-matmul
            *(_Float16*)(wp + mt * 8192) = (_Float16)hv;     // imm-offset ds_write_b16
          }
        }
      }
    }
    __syncthreads();
  };

  run_layer(std::integral_constant<int, 1>{}, wsh, b_in);
  #pragma clang loop unroll(disable)
  for (int L = 0; L < NMID; ++L)
    run_layer(std::integral_constant<int, 8>{}, wsh + WIN_ELEMS + L * WL_ELEMS, b_mid + L * DIM);

  // ---------------- output layer: out = (alpha*relu h).W_out / alpha + b_out ----
  // R9 vectorized epilogue: 8x ds_read_b128 + 16x float4 W_out loads per thread.
  {
    int m = tid >> 2, seg = tid & 3;          // m 0..127; same-m threads adjacent -> shuffle reduce
    float sum = 0.f;
    #pragma unroll
    for (int i = 0; i < 8; ++i) {
      int k = (seg << 6) + (i << 3);          // 8-aligned group within this thread's 64-wide segment
      half8 hv = *(const half8*)&hs[sw_idx(m, k)];
      float4 w0 = *(const float4*)&W_out[k];
      float4 w1 = *(const float4*)&W_out[k + 4];
      sum += (float)hv[0] * w0.x + (float)hv[1] * w0.y
           + (float)hv[2] * w0.z + (float)hv[3] * w0.w
           + (float)hv[4] * w1.x + (float)hv[5] * w1.y
           + (float)hv[6] * w1.z + (float)hv[7] * w1.w;
    }
    sum += __shfl_xor(sum, 1);
    sum += __shfl_xor(sum, 2);
    if (seg == 0) out[rbase + m] = sum * INV_ALPHA + b_out[0];
  }
}

extern "C" void kernel_launch(void* const* d_in, const int* in_sizes, int n_in,
                              void* d_out, int out_size, void* d_ws, size_t ws_size,
                              hipStream_t stream)
{
  const float* x      = (const float*)d_in[0];
  const float* table1 = (const float*)d_in[1];
  const float* table2 = (const float*)d_in[2];
  const float* W_in   = (const float*)d_in[3];
  const float* b_in   = (const float*)d_in[4];
  const float* W_mid  = (const float*)d_in[5];
  const float* b_mid  = (const float*)d_in[6];
  const float* W_out  = (const float*)d_in[7];
  const float* b_out  = (const float*)d_in[8];
  float* out  = (float*)d_out;
  _Float16* wsh = (_Float16*)d_ws;

  // Resolutions: identical double-precision op sequence as the Python module (same libm).
  double b = exp((log(512.0) - log(16.0)) / 3.0);
  int res[4];
  for (int l = 0; l < 4; ++l) res[l] = (int)floor(16.0 * pow(b, (double)l));

  int prep_total = WIN_ELEMS + 6 * WL_ELEMS;   // 401408 = 1568 * 256
  prep_weights<<<prep_total / 256, 256, 0, stream>>>(W_in, W_mid, wsh);
  mlp_fused<<<NRAYS / MBLK, NTHR, 0, stream>>>(x, table1, table2, wsh, b_in, b_mid,
                                               W_out, b_out, out,
                                               res[0], res[1], res[2], res[3]);
}

// Round 8
// 293.228 us; speedup vs baseline: 1.0094x; 1.0094x over previous
//
#include <hip/hip_runtime.h>
#include <type_traits>
#include <cmath>
#include <cstdint>

#define NRAYS     262144
#define HASHMAP   524288
#define DIM       256
#define NMID      6
#define MBLK      64
#define ALPHA     512.0f          // power-of-2 activation scale: lifts h (~1e-4) out of
#define INV_ALPHA (1.0f / 512.0f) // fp16 subnormal range; exact, removed at output.

typedef _Float16 half8 __attribute__((ext_vector_type(8)));
typedef _Float16 half2 __attribute__((ext_vector_type(2)));
typedef float  floatx4 __attribute__((ext_vector_type(4)));

// ws layout (_Float16 elements) — fp16 weights, single product per MFMA:
//   [0, 8192):        W_in  fragments [nc:16][lane:64][j:8]  (K padded 16->32 with zeros)
//   [8192, 401408):   W_mid fragments [L:6][kc:8][nc:16][lane:64][j:8]
// fp16 numerics validated: absmax 1.19e-7, 3.3x under threshold.
//
// SESSION INVARIANT (R10/R11/R14 post-mortems): the ~2-7e-6 few-elements-wrong
// miscompile class fires on ANY novel MFMA-loop register shape. The ONLY
// trusted micro-structure is R13's exact per-wave loop:
//   b[4]+a[4] input regs, acc[4][4] floatx4, one setprio cluster, nl=4,
//   #pragma clang loop unroll(disable) on kc. NEVER deviate from it.
//
// R12 (pass, 326us): strength-reduced A addressing + s_setprio.
// R13 (pass, 222us): strength-reduced epilogue addressing.
// R15 (pass, 238us): MBLK=128 NEUTRAL-NEGATIVE — FETCH identical (16.3MB) to
//   R13 => weights already L2-resident; weight-BW theory dead. REVERTED.
// R16: bias folded into MFMA C-in (acc init = bias splat, not zeros).
//   Removes per layer/wave: 64 v_add_f32 (epilogue VALU was 78% of the 48%
//   VALUBusy) AND the post-barrier bias-load L2 stall. Zero extra live state
//   across the kc loop (bv[4] dies at acc-init). Numerics: bias enters the
//   f32 sum first instead of last — <=1 ulp f32 reorder, far below the fp16
//   quantization floor.
#define WIN_ELEMS   8192
#define WL_ELEMS    65536
#define WKC_ELEMS   8192
#define WNC_ELEMS   512

// Gray-coded XOR swizzle (R4, frozen — conflict counter insensitive to choice).
__device__ __forceinline__ int sw_idx(int r, int k) {
  int s = (r ^ (r >> 1)) & 7;
  return (r << 8) + ((((k >> 3) ^ s) << 3) | (k & 7));
}

__global__ __launch_bounds__(256) void prep_weights(
    const float* __restrict__ W_in, const float* __restrict__ W_mid,
    _Float16* __restrict__ wsh)
{
  int tid = blockIdx.x * 256 + threadIdx.x;
  int pos = tid & 511;             // lane*8 + j
  int lane = pos >> 3, j = pos & 7;
  int kk = ((lane >> 4) << 3) + j; // quad*8 + j, 0..31
  if (tid < WIN_ELEMS) {
    int nc = tid >> 9;
    int n = (nc << 4) + (lane & 15);
    float v = (kk < 16) ? W_in[kk * DIM + n] : 0.f;
    wsh[nc * WNC_ELEMS + pos] = (_Float16)v;
  } else if (tid < WIN_ELEMS + 6 * WL_ELEMS) {
    int u = tid - WIN_ELEMS;
    int fid = u >> 9;              // 0..767
    int L   = fid >> 7;
    int rem = fid & 127;
    int kc  = rem >> 4;
    int nc  = rem & 15;
    int k = (kc << 5) + kk;
    int n = (nc << 4) + (lane & 15);
    float v = W_mid[L * (DIM * DIM) + k * DIM + n];
    wsh[WIN_ELEMS + L * WL_ELEMS + kc * WKC_ELEMS + nc * WNC_ELEMS + pos] = (_Float16)v;
  }
}

// (256,4): VGPR cap 128 (the correctness invariant) AND 4 blocks/CU (32 KB LDS)
// for cross-block phase overlap. Latency hiding via TLP (16 waves/CU), not
// register prefetch: per kc, 4 waves x 16 MFMA (~300 cyc/SIMD) covers ~200-cyc
// L2 latency of the un-prefetched weight loads.
__global__ __launch_bounds__(256, 4) void mlp_fused(
    const float* __restrict__ x,
    const float* __restrict__ table1,
    const float* __restrict__ table2,
    const _Float16* __restrict__ wsh,
    const float* __restrict__ b_in,
    const float* __restrict__ b_mid,
    const float* __restrict__ W_out,
    const float* __restrict__ b_out,
    float* __restrict__ out,
    int res0, int res1, int res2, int res3)
{
  __shared__ __align__(16) _Float16 hs[MBLK * 256];  // alpha*relu(h) in fp16, swizzled [ray][k]

  const int tid  = threadIdx.x;
  const int lane = tid & 63;
  const int wave = tid >> 6;
  const int col  = lane & 15;
  const int quad = lane >> 4;
  const int rbase = blockIdx.x * MBLK;

  // ---------------- hash-grid encode: 512 (ray,enc,level) tasks, 2 per thread ----------------
  #pragma unroll
  for (int i = 0; i < 2; ++i) {
    int task = tid + (i << 8);
    int r   = task & 63;
    int el  = task >> 6;           // 0..7
    int enc = el >> 2, lev = el & 3;
    const float* xp = x + (size_t)(rbase + r) * 4 + enc * 2;
    float px = xp[0], py = xp[1];
    int res = (lev == 0) ? res0 : (lev == 1) ? res1 : (lev == 2) ? res2 : res3;
    float fres = (float)res;
    float xf = px * fres, yf = py * fres;
    float xi = floorf(xf), yi = floorf(yf);
    float fx = xf - xi,  fy = yf - yi;
    uint32_t ix = (uint32_t)xi, iy = (uint32_t)yi;
    const float2* tab = (const float2*)(enc ? table2 : table1) + (size_t)lev * HASHMAP;
    float f0 = 0.f, f1 = 0.f;
    #pragma unroll
    for (int c = 0; c < 4; ++c) {                    // corners (0,0),(0,1),(1,0),(1,1)
      uint32_t c0 = (uint32_t)(c >> 1), c1 = (uint32_t)(c & 1);
      uint32_t h = ((ix + c0) ^ ((iy + c1) * 2654435761u)) & (uint32_t)(HASHMAP - 1);
      float2 v = tab[h];
      float w = (c0 ? fx : 1.f - fx) * (c1 ? fy : 1.f - fy);
      f0 += w * v.x;
      f1 += w * v.y;
    }
    int cb = enc * 8 + lev * 2;                      // emb column (concat: enc-major, level, feat)
    half2 hp = {(_Float16)(f0 * ALPHA), (_Float16)(f1 * ALPHA)};
    *(half2*)&hs[sw_idx(r, cb)] = hp;
  }
  // zero K-pad columns 16..31 for the first (K=32) MFMA
  for (int i = tid; i < MBLK * 16; i += 256) {
    int r = i >> 4, k = 16 + (i & 15);
    hs[sw_idx(r, k)] = (_Float16)0.f;
  }
  __syncthreads();

  floatx4 acc[4][4];

  // R12 A-address strength reduction. For A-reads, row = mt*16+col so row&7 =
  // col&7 and sw_idx's s is mt-independent:
  //   byte(mt,kc) = (mt*16+col)*512 + qa*16 + ((kc^s2)<<6)
  //   s_a=(col^(col>>1))&7, s2=s_a>>2, qa=quad^(s_a&3).
  // Exactly 2*sw_idx(mt*16+col, kc*32+quad*8) — verified algebraically (R3).
  // mt term (mt*8192) folds into the ds_read immediate offset.
  const int s_a = (col ^ (col >> 1)) & 7;
  const int s2  = (s_a >> 2) & 1;
  const int abase = col * 512 + (quad ^ (s_a & 3)) * 16;
  const char* const hsb = (const char*)hs;

  // One dense layer: D(64x256) = A(64xK) * B(Kx256) + bias (via MFMA C-in);
  // A = alpha*h (fp16, LDS), B = fp16 weights (pre-permuted fragments).
  auto run_layer = [&](auto kc_const, const _Float16* __restrict__ wbase,
                       const float* __restrict__ bias_ptr) {
    constexpr int KCOUNT = decltype(kc_const)::value;

    // R16: bias-in-acc-init. D layout: col = lane&15 -> all 4 regs of a lane
    // share n = wave*64 + nl*16 + col, so acc[mt][nl] = splat(bias[n]*ALPHA).
    // bv[] dies here — no live state added across the kc loop.
    {
      float bv[4];
      #pragma unroll
      for (int nl = 0; nl < 4; ++nl)
        bv[nl] = bias_ptr[wave * 64 + nl * 16 + col] * ALPHA;
      #pragma unroll
      for (int mt = 0; mt < 4; ++mt)
        #pragma unroll
        for (int nl = 0; nl < 4; ++nl)
          acc[mt][nl] = (floatx4){bv[nl], bv[nl], bv[nl], bv[nl]};
    }

    const _Float16* wlane = wbase + wave * 4 * WNC_ELEMS + lane * 8;

    #pragma clang loop unroll(disable)               // keep VGPR pressure flat (<=128)
    for (int kc = 0; kc < KCOUNT; ++kc) {
      half8 b[4];
      const _Float16* wk = wlane + kc * WKC_ELEMS;
      #pragma unroll
      for (int nl = 0; nl < 4; ++nl)
        b[nl] = *(const half8*)(wk + nl * WNC_ELEMS);
      half8 a[4];
      const char* ap = hsb + abase + ((kc ^ s2) << 6);
      #pragma unroll
      for (int mt = 0; mt < 4; ++mt)
        a[mt] = *(const half8*)(ap + mt * 8192);     // imm-offset ds_read_b128
      __builtin_amdgcn_s_setprio(1);
      #pragma unroll
      for (int nl = 0; nl < 4; ++nl)
        #pragma unroll
        for (int mt = 0; mt < 4; ++mt)
          acc[mt][nl] = __builtin_amdgcn_mfma_f32_16x16x32_f16(a[mt], b[nl], acc[mt][nl], 0, 0, 0);
      __builtin_amdgcn_s_setprio(0);
    }
    __syncthreads();   // all waves done reading hs before overwrite

    // R13 epilogue address strength reduction. Write target (m,n):
    //   m = mt*16 + quad*4 + r, n = wave*64 + nl*16 + col.
    //   byte = mt*8192 (ds imm) + (quad*4+r)*512 + wave*128
    //        + ((v^s_r)<<4) + (col&7)*2,  v = nl*2|c3, s_r=(m0^(m0>>1))&7.
    // R16: bias already inside acc — epilogue is fmax + cvt + write only.
    {
      const int c3   = (col >> 3) & 1;
      const int ebase = wave * 128 + ((col & 7) << 1);
      #pragma unroll
      for (int nl = 0; nl < 4; ++nl) {
        #pragma unroll
        for (int r = 0; r < 4; ++r) {
          int m0  = quad * 4 + r;
          int s_r = (m0 ^ (m0 >> 1)) & 7;
          int va  = m0 * 512 + ebase + (((((nl << 1) | c3)) ^ s_r) << 4);
          char* wp = (char*)hs + va;
          #pragma unroll
          for (int mt = 0; mt < 4; ++mt) {
            float hv = fmaxf(acc[mt][nl][r], 0.f);           // ReLU pre-next-matmul
            *(_Float16*)(wp + mt * 8192) = (_Float16)hv;     // imm-offset ds_write_b16
          }
        }
      }
    }
    __syncthreads();
  };

  run_layer(std::integral_constant<int, 1>{}, wsh, b_in);
  #pragma clang loop unroll(disable)
  for (int L = 0; L < NMID; ++L)
    run_layer(std::integral_constant<int, 8>{}, wsh + WIN_ELEMS + L * WL_ELEMS, b_mid + L * DIM);

  // ---------------- output layer: out = (alpha*relu h).W_out / alpha + b_out ----
  // R9: vectorized epilogue. sw_idx keeps k's low 3 bits contiguous, so an
  // 8-aligned half8 LDS read is legal: 8x ds_read_b128 + 16x float4 W_out loads
  // replace 64 ds_read_u16 + 64 scalar global loads per thread.
  {
    int m = tid >> 2, seg = tid & 3;          // same-m threads adjacent -> shuffle reduce
    float sum = 0.f;
    #pragma unroll
    for (int i = 0; i < 8; ++i) {
      int k = (seg << 6) + (i << 3);          // 8-aligned group within this thread's 64-wide segment
      half8 hv = *(const half8*)&hs[sw_idx(m, k)];
      float4 w0 = *(const float4*)&W_out[k];
      float4 w1 = *(const float4*)&W_out[k + 4];
      sum += (float)hv[0] * w0.x + (float)hv[1] * w0.y
           + (float)hv[2] * w0.z + (float)hv[3] * w0.w
           + (float)hv[4] * w1.x + (float)hv[5] * w1.y
           + (float)hv[6] * w1.z + (float)hv[7] * w1.w;
    }
    sum += __shfl_xor(sum, 1);
    sum += __shfl_xor(sum, 2);
    if (seg == 0) out[rbase + m] = sum * INV_ALPHA + b_out[0];
  }
}

extern "C" void kernel_launch(void* const* d_in, const int* in_sizes, int n_in,
                              void* d_out, int out_size, void* d_ws, size_t ws_size,
                              hipStream_t stream)
{
  const float* x      = (const float*)d_in[0];
  const float* table1 = (const float*)d_in[1];
  const float* table2 = (const float*)d_in[2];
  const float* W_in   = (const float*)d_in[3];
  const float* b_in   = (const float*)d_in[4];
  const float* W_mid  = (const float*)d_in[5];
  const float* b_mid  = (const float*)d_in[6];
  const float* W_out  = (const float*)d_in[7];
  const float* b_out  = (const float*)d_in[8];
  float* out  = (float*)d_out;
  _Float16* wsh = (_Float16*)d_ws;

  // Resolutions: identical double-precision op sequence as the Python module (same libm).
  double b = exp((log(512.0) - log(16.0)) / 3.0);
  int res[4];
  for (int l = 0; l < 4; ++l) res[l] = (int)floor(16.0 * pow(b, (double)l));

  int prep_total = WIN_ELEMS + 6 * WL_ELEMS;   // 401408 = 1568 * 256
  prep_weights<<<prep_total / 256, 256, 0, stream>>>(W_in, W_mid, wsh);
  mlp_fused<<<NRAYS / MBLK, 256, 0, stream>>>(x, table1, table2, wsh, b_in, b_mid,
                                              W_out, b_out, out,
                                              res[0], res[1], res[2], res[3]);
}